// Round 7
// baseline (171.032 us; speedup 1.0000x reference)
//
#include <hip/hip_runtime.h>

// Problem: B=256, T=256 trees, E=64, H=4.
// out[b,t,e] = sum_{j!=t,h} relu(x[b,j,:]·W1[t,j,:,h] + b1[t,j,h]) * W2[t,pos(j)*4+h,e] + b2[t,e]
//
// R7: kill request fragmentation on BOTH H sides.
//   H layout: [i][32 joct][256 b][32 k] u16 -> phaseA writes 8KB contiguous spans,
//   lane-contiguous (q in fastest lane bits); phaseB reads same spans lane-contiguous.
//   W2Z[t][e][1024]: transpose + off-diag shift + j==t zeroing done ONCE in w2z_kernel,
//   so phaseB stageB is a contiguous copy.
// Fallback (small ws): R4 monolithic fused kernel.

namespace {

constexpr int T_ = 256;
constexpr int E_ = 64;
constexpr int K2_ = 1020;           // (T-1)*H

typedef float  f32x4  __attribute__((ext_vector_type(4)));
typedef short  bf16x8 __attribute__((ext_vector_type(8)));
typedef unsigned short u16x4 __attribute__((ext_vector_type(4)));

__device__ inline unsigned short f2b(float f) {
    union { float f; unsigned u; } v; v.f = f;
    unsigned r = v.u + 0x7fffu + ((v.u >> 16) & 1u);   // RNE bf16
    return (unsigned short)(r >> 16);
}

__device__ inline bf16x8 pack8(f32x4 a, f32x4 b) {
    bf16x8 r;
    r[0] = (short)f2b(a[0]); r[1] = (short)f2b(a[1]);
    r[2] = (short)f2b(a[2]); r[3] = (short)f2b(a[3]);
    r[4] = (short)f2b(b[0]); r[5] = (short)f2b(b[1]);
    r[6] = (short)f2b(b[2]); r[7] = (short)f2b(b[3]);
    return r;
}

// R4 fallback LDS geometry
constexpr int JC = 4;
constexpr int CHUNKS = 16;
constexpr int W1_ROW   = 72;
constexpr int W1_PLANE = 32 * W1_ROW + 8;
constexpr int PB_ROW   = 24;
constexpr int PB_PLANE = 64 * PB_ROW + 8;
constexpr int W2_ROW   = 16;
constexpr int W2_PLANE = 64 * W2_ROW + 8;

} // namespace

// ======================= shared helpers =======================

// x[b][j][e] f32 -> xT[j][b][e] bf16
__global__ __launch_bounds__(256) void xcast_kernel(
    const float* __restrict__ x, unsigned short* __restrict__ xT)
{
    const int g     = blockIdx.x * 256 + threadIdx.x;   // 262,144
    const int part  = g & 3;                            // 16 e's each
    const int rowid = g >> 2;                           // = b*256 + j
    const int b = rowid >> 8, j = rowid & 255;
    const float* src = x + (size_t)rowid * E_ + part * 16;
    f32x4 v0 = *(const f32x4*)(src);
    f32x4 v1 = *(const f32x4*)(src + 4);
    f32x4 v2 = *(const f32x4*)(src + 8);
    f32x4 v3 = *(const f32x4*)(src + 12);
    unsigned short* dst = xT + ((size_t)j * 256 + b) * E_ + part * 16;
    *(bf16x8*)(dst)     = pack8(v0, v1);
    *(bf16x8*)(dst + 8) = pack8(v2, v3);
}

// out[b,t,e] = b2[t,e] (fallback path only)
__global__ __launch_bounds__(256) void init_out_kernel(
    const float* __restrict__ b2, float* __restrict__ out)
{
    const int idx = blockIdx.x * 256 + threadIdx.x;
    ((f32x4*)out)[idx] = ((const f32x4*)b2)[idx & 4095];
}

// ======================= two-phase path =======================

// W2[t][k][e] f32 -> W2Z[t][e][kz] bf16 where kz = 4j+h, value = (j==t)?0:W2[t][pos(j)*4+h][e].
// The off-diagonal gather happens HERE (once), so phaseB staging is contiguous.
__global__ __launch_bounds__(512, 2) void w2z_kernel(
    const float* __restrict__ W2, unsigned short* __restrict__ W2Z)
{
    __shared__ __align__(16) unsigned short sT[64][136];
    const int bid = blockIdx.x;
    const int t = bid >> 3, kb = bid & 7;               // 8 k-blocks of 128
    const int tid = threadIdx.x;
    {
        const int kl = tid >> 2;            // 0..127 (block-local dst k)
        const int e0 = (tid & 3) << 4;      // 0,16,32,48
        const int k  = kb * 128 + kl;       // dst kz, 0..1023
        const int j  = k >> 2, h = k & 3;
        f32x4 v0 = {0,0,0,0}, v1 = {0,0,0,0}, v2 = {0,0,0,0}, v3 = {0,0,0,0};
        if (j != t) {
            const int ksrc = ((j < t) ? j : j - 1) * 4 + h;   // 0..1019
            const float* src = W2 + ((size_t)t * K2_ + ksrc) * E_ + e0;
            v0 = *(const f32x4*)(src);
            v1 = *(const f32x4*)(src + 4);
            v2 = *(const f32x4*)(src + 8);
            v3 = *(const f32x4*)(src + 12);
        }
        #pragma unroll
        for (int m = 0; m < 4; ++m) {
            sT[e0 + m     ][kl] = f2b(v0[m]);
            sT[e0 + 4 + m ][kl] = f2b(v1[m]);
            sT[e0 + 8 + m ][kl] = f2b(v2[m]);
            sT[e0 + 12 + m][kl] = f2b(v3[m]);
        }
    }
    __syncthreads();
    {
        const int e  = tid >> 3;            // 0..63
        const int ko = tid & 7;             // 16 k's each
        const unsigned short* srow = &sT[e][ko * 16];
        bf16x8 a = *(const bf16x8*)(srow);
        bf16x8 b = *(const bf16x8*)(srow + 8);
        unsigned short* dst = W2Z + ((size_t)t * 64 + e) * 1024 + kb * 128 + ko * 16;
        *(bf16x8*)(dst)     = a;
        *(bf16x8*)(dst + 8) = b;
    }
}

// Phase A: grid (32 joct-swz, n_it, 2 bh), 256 threads (4 waves).
// Block: 8 j's x 16 trees x 128 b. Per iq (4 trees): MFMA (m=(il,h), n=b),
// relu+bias -> sH[il][b][k32] -> lane-contiguous 8KB-span flush to H[i][joct][b][32].
__global__ __launch_bounds__(256, 3) void phaseA2_kernel(
    const unsigned short* __restrict__ xT,  // [j][b][e]
    const float* __restrict__ W1,           // [256][256][64][4]
    const float* __restrict__ b1,           // [256][256][4]
    unsigned short* __restrict__ H,         // [TS][32 joct][256 b][32 k]
    int i_gbase, int n_it)
{
    __shared__ __align__(16) unsigned short sA[8][16][68];   // [j][m=il*4+h][e] 17408B
    __shared__ __align__(16) unsigned short sH[4][128][34];  // [il][b][k]       34816B

    // joct swizzle: XCD x (= gid%8) gets jocts {4x..4x+3} -> xT slice L2-resident.
    const int bx   = blockIdx.x;                 // 0..31
    const int joct = (bx & 7) * 4 + (bx >> 3);
    const int it   = blockIdx.y;
    const int bh   = blockIdx.z;
    const int j0   = joct * 8;

    const int tid = threadIdx.x;
    const int w = tid >> 6, lane = tid & 63, r16 = lane & 15, kg = lane >> 4;
    const int bW = w * 32;                       // wave's local b-base (of 128)

    // ---- x fragments, register-resident across all iq (B operand) ----
    bf16x8 xf[8][2][2];
    #pragma unroll
    for (int j = 0; j < 8; ++j)
        #pragma unroll
        for (int nt = 0; nt < 2; ++nt) {
            const unsigned short* xr =
                xT + ((size_t)(j0 + j) * 256 + bh * 128 + bW + nt * 16 + r16) * 64;
            xf[j][nt][0] = *(const bf16x8*)(xr + kg * 8);
            xf[j][nt][1] = *(const bf16x8*)(xr + 32 + kg * 8);
        }

    auto stageA = [&](int iq) {
        const int p = tid >> 3, seg = tid & 7;   // p: il*8+j ; seg: 32 f32 each
        const int il = p >> 3, j = p & 7;
        const int ig = i_gbase + it * 16 + iq * 4 + il;
        const float* src = W1 + ((size_t)ig * 256 + (j0 + j)) * 256 + seg * 32;
        f32x4 v[8];
        #pragma unroll
        for (int s4 = 0; s4 < 8; ++s4) v[s4] = *(const f32x4*)(src + s4 * 4);
        // v[s4][q]: e = seg*8+s4, h = q. Vectorized per-h b128 LDS writes.
        #pragma unroll
        for (int h = 0; h < 4; ++h) {
            bf16x8 pk;
            #pragma unroll
            for (int s4 = 0; s4 < 8; ++s4) pk[s4] = (short)f2b(v[s4][h]);
            *(bf16x8*)&sA[j][il * 4 + h][seg * 8] = pk;
        }
    };

    // Lane-contiguous flush: per iq the block owns 4 x 8KB contiguous H spans.
    // idx = (il, b, q) with q in the fastest bits -> consecutive lanes write
    // consecutive 16B -> 64 lanes = 1KB contiguous = 16 full-line requests.
    auto flushH = [&](int iq) {
        #pragma unroll
        for (int it8 = 0; it8 < 8; ++it8) {
            const int idx = it8 * 256 + tid;      // 0..2047
            const int il  = idx >> 9;             // 0..3
            const int b   = (idx >> 2) & 127;
            const int q   = idx & 3;
            const int i   = it * 16 + iq * 4 + il;
            bf16x8 v = *(const bf16x8*)&sH[il][b][q * 8];
            *(bf16x8*)(H + (((size_t)i * 32 + joct) * 256 + bh * 128 + b) * 32 + q * 8) = v;
        }
    };

    for (int iq = 0; iq < 4; ++iq) {
        stageA(iq);
        if (iq > 0) flushH(iq - 1);
        __syncthreads();

        // ---- compute: D[m=(il,h)][n=b] = W1 · x ; lane: il=kg, h=reg, b=nt*16+r16 ----
        #pragma unroll
        for (int j = 0; j < 8; ++j) {
            const unsigned short* ar = &sA[j][r16][0];
            bf16x8 a0 = *(const bf16x8*)(ar + kg * 8);
            bf16x8 a1 = *(const bf16x8*)(ar + 32 + kg * 8);
            const int iS = it * 16 + iq * 4 + kg;          // slice-local tree
            f32x4 bias = *(const f32x4*)(b1 + ((size_t)(i_gbase + iS) * 256 + (j0 + j)) * 4);
            #pragma unroll
            for (int nt = 0; nt < 2; ++nt) {
                f32x4 acc = (f32x4){0.f, 0.f, 0.f, 0.f};
                acc = __builtin_amdgcn_mfma_f32_16x16x32_bf16(a0, xf[j][nt][0], acc, 0, 0, 0);
                acc = __builtin_amdgcn_mfma_f32_16x16x32_bf16(a1, xf[j][nt][1], acc, 0, 0, 0);
                float v0 = acc[0] + bias[0]; v0 = v0 > 0.f ? v0 : 0.f;
                float v1 = acc[1] + bias[1]; v1 = v1 > 0.f ? v1 : 0.f;
                float v2 = acc[2] + bias[2]; v2 = v2 > 0.f ? v2 : 0.f;
                float v3 = acc[3] + bias[3]; v3 = v3 > 0.f ? v3 : 0.f;
                uint2 pk;
                pk.x = (unsigned)f2b(v0) | ((unsigned)f2b(v1) << 16);
                pk.y = (unsigned)f2b(v2) | ((unsigned)f2b(v3) << 16);
                *(uint2*)&sH[kg][bW + nt * 16 + r16][j * 4] = pk;
            }
        }
        __syncthreads();
    }
    flushH(3);
}

// Phase B: block = (tree, b-half). out[b][t][:] = sum_k H2[b][k] W2Z[t][:][k] + b2.
// M=128, N=64, K=1024 (zero-padded) in 16 chunks of 64; persistent acc.
__global__ __launch_bounds__(512, 4) void phaseB_kernel(
    const unsigned short* __restrict__ H,    // [TS][32][256][32]
    const unsigned short* __restrict__ W2Z,  // [256][64][1024]
    const float* __restrict__ b2,            // [256][64]
    float* __restrict__ out,                 // [256][256][64]
    int i_base)
{
    __shared__ __align__(16) unsigned short sA[2][128][72];  // [b][kk] 36.9KB
    __shared__ __align__(16) unsigned short sB[2][64][72];   // [e][kk] 18.4KB

    const int bid = blockIdx.x;
    const int t_loc = bid >> 1;
    const int t  = i_base + t_loc;
    const int b0 = (bid & 1) << 7;
    const int tid = threadIdx.x;
    const int w = tid >> 6, lane = tid & 63, r16 = lane & 15, kg = lane >> 4;

    // chunk c covers k in [c*64,(c+1)*64) = jocts {2c, 2c+1}; lane-contiguous reads.
    auto stageA = [&](int c, int pb) {
        #pragma unroll
        for (int half = 0; half < 2; ++half) {
            const int idx = half * 512 + tid;     // 0..1023 over [jh][b][q]
            const int jh  = idx >> 9;             // 0..1
            const int b   = (idx >> 2) & 127;
            const int q   = idx & 3;
            const unsigned short* src =
                H + (((size_t)t_loc * 32 + 2 * c + jh) * 256 + b0 + b) * 32 + q * 8;
            bf16x8 v = *(const bf16x8*)src;
            *(bf16x8*)&sA[pb][b][jh * 32 + q * 8] = v;
        }
    };
    // contiguous copy: W2Z row [t][e][c*64 .. +64]
    auto stageB = [&](int c, int pb) {
        const int e = tid >> 3;       // 0..63
        const int q = tid & 7;        // 0..7
        bf16x8 v = *(const bf16x8*)(W2Z + ((size_t)t * 64 + e) * 1024 + c * 64 + q * 8);
        *(bf16x8*)&sB[pb][e][q * 8] = v;
    };

    stageA(0, 0); stageB(0, 0);
    __syncthreads();

    f32x4 acc[4];
    #pragma unroll
    for (int nt = 0; nt < 4; ++nt) acc[nt] = (f32x4){0.f, 0.f, 0.f, 0.f};

    for (int c = 0; c < 16; ++c) {
        const int pb = c & 1;
        if (c + 1 < 16) { stageA(c + 1, pb ^ 1); stageB(c + 1, pb ^ 1); }

        const unsigned short* ar = &sA[pb][w * 16 + r16][0];
        bf16x8 a0 = *(const bf16x8*)(ar + kg * 8);
        bf16x8 a1 = *(const bf16x8*)(ar + 32 + kg * 8);
        #pragma unroll
        for (int nt = 0; nt < 4; ++nt) {
            const unsigned short* br = &sB[pb][nt * 16 + r16][0];
            bf16x8 bb0 = *(const bf16x8*)(br + kg * 8);
            bf16x8 bb1 = *(const bf16x8*)(br + 32 + kg * 8);
            acc[nt] = __builtin_amdgcn_mfma_f32_16x16x32_bf16(a0, bb0, acc[nt], 0, 0, 0);
            acc[nt] = __builtin_amdgcn_mfma_f32_16x16x32_bf16(a1, bb1, acc[nt], 0, 0, 0);
        }
        __syncthreads();
    }

    #pragma unroll
    for (int nt = 0; nt < 4; ++nt) {
        const int e = nt * 16 + r16;
        const float bias = b2[(t << 6) + e];
        #pragma unroll
        for (int r = 0; r < 4; ++r) {
            const int b = b0 + w * 16 + kg * 4 + r;
            out[((size_t)b << 14) + (t << 6) + e] = acc[nt][r] + bias;
        }
    }
}

// ======================= fallback: R4 monolithic fused kernel =======================

template <bool XBF>
__global__ __launch_bounds__(512, 4) void fused_forest_kernel(
    const void*  __restrict__ xv,
    const float* __restrict__ W1,
    const float* __restrict__ b1,
    const float* __restrict__ W2,
    float* __restrict__ out)
{
    __shared__ __align__(16) unsigned short sW1[4 * W1_PLANE];
    __shared__ __align__(16) unsigned short sPB[8 * PB_PLANE];
    __shared__ __align__(16) unsigned short sW2[2][8 * W2_PLANE];
    __shared__ __align__(16) float sB1[4][32];

    const int bid = blockIdx.x;
    const int xcd = bid & 7;
    const int rr  = bid >> 3;
    const int tgl = rr >> 4;
    const int bg  = (rr >> 2) & 3;
    const int jg  = rr & 3;
    const int tg  = tgl * 8 + xcd;
    const int i0  = tg << 3;
    const int b0  = bg << 6;
    const int j0g = jg << 6;

    const int tid  = threadIdx.x;
    const int w    = tid >> 6;
    const int lane = tid & 63;
    const int r16  = lane & 15;
    const int kg   = lane >> 4;
    const int bt   = w & 3;
    const int mh   = w >> 2;

    f32x4 acc[4][4];
    #pragma unroll
    for (int mt = 0; mt < 4; ++mt)
        #pragma unroll
        for (int nt = 0; nt < 4; ++nt)
            acc[mt][nt] = (f32x4){0.f, 0.f, 0.f, 0.f};

    auto stage = [&](int c, int pb) {
        const int j0 = j0g + c * JC;
        if (tid < 128) {
            const int jj = tid >> 5, ih = tid & 31;
            sB1[jj][ih] = b1[((i0 + (ih >> 2)) * T_ + (j0 + jj)) * 4 + (ih & 3)];
        }
        {
            const float* src = W1 + (((size_t)(i0 + w) * T_ + (j0 + kg)) * E_) * 4 + r16 * 16;
            f32x4 v0 = *(const f32x4*)(src);
            f32x4 v1 = *(const f32x4*)(src + 4);
            f32x4 v2 = *(const f32x4*)(src + 8);
            f32x4 v3 = *(const f32x4*)(src + 12);
            #pragma unroll
            for (int h = 0; h < 4; ++h) {
                u16x4 pk = (u16x4){f2b(v0[h]), f2b(v1[h]), f2b(v2[h]), f2b(v3[h])};
                *(u16x4*)&sW1[kg * W1_PLANE + (w * 4 + h) * W1_ROW + r16 * 4] = pk;
            }
        }
        {
            const int kk   = lane >> 2;
            const int e0   = (lane & 3) * 16;
            const int tabs = i0 + w;
            const int j    = j0 + (kk >> 2);
            unsigned short* dst = &sW2[pb][w * W2_PLANE + kk];
            if (j == tabs) {
                #pragma unroll
                for (int q = 0; q < 16; ++q) dst[(e0 + q) * W2_ROW] = 0;
            } else {
                const int ksrc = ((j < tabs) ? j : j - 1) * 4 + (kk & 3);
                const float* src = W2 + ((size_t)tabs * K2_ + ksrc) * E_ + e0;
                f32x4 v0 = *(const f32x4*)(src);
                f32x4 v1 = *(const f32x4*)(src + 4);
                f32x4 v2 = *(const f32x4*)(src + 8);
                f32x4 v3 = *(const f32x4*)(src + 12);
                #pragma unroll
                for (int q = 0; q < 4; ++q) {
                    dst[(e0 + q)      * W2_ROW] = f2b(v0[q]);
                    dst[(e0 + 4 + q)  * W2_ROW] = f2b(v1[q]);
                    dst[(e0 + 8 + q)  * W2_ROW] = f2b(v2[q]);
                    dst[(e0 + 12 + q) * W2_ROW] = f2b(v3[q]);
                }
            }
        }
    };

    stage(0, 0);
    __syncthreads();

    const int brow = b0 + bt * 16 + r16;

    for (int c = 0; c < CHUNKS; ++c) {
        const int j0 = j0g + c * JC;
        #pragma unroll
        for (int jj = 0; jj < JC; ++jj) {
            bf16x8 xa, xc;
            if (XBF) {
                const unsigned short* xr =
                    (const unsigned short*)xv + ((size_t)(j0 + jj) * 256 + brow) * E_;
                xa = *(const bf16x8*)(xr + kg * 8);
                xc = *(const bf16x8*)(xr + 32 + kg * 8);
            } else {
                const float* xr = (const float*)xv + ((size_t)brow * T_ + (j0 + jj)) * E_ + kg * 8;
                xa = pack8(*(const f32x4*)xr, *(const f32x4*)(xr + 4));
                xc = pack8(*(const f32x4*)(xr + 32), *(const f32x4*)(xr + 36));
            }
            const unsigned short* wr = &sW1[jj * W1_PLANE + (mh * 16 + r16) * W1_ROW];
            bf16x8 wa = *(const bf16x8*)(wr + kg * 8);
            bf16x8 wc = *(const bf16x8*)(wr + 32 + kg * 8);
            f32x4 cf = (f32x4){0.f, 0.f, 0.f, 0.f};
            cf = __builtin_amdgcn_mfma_f32_16x16x32_bf16(wa, xa, cf, 0, 0, 0);
            cf = __builtin_amdgcn_mfma_f32_16x16x32_bf16(wc, xc, cf, 0, 0, 0);
            const int i = mh * 4 + kg;
            f32x4 bias = *(const f32x4*)&sB1[jj][i * 4];
            #pragma unroll
            for (int r = 0; r < 4; ++r) {
                float vv = cf[r] + bias[r];
                cf[r] = vv > 0.f ? vv : 0.f;
            }
            unsigned p0 = (unsigned)f2b(cf[0]) | ((unsigned)f2b(cf[1]) << 16);
            unsigned p1 = (unsigned)f2b(cf[2]) | ((unsigned)f2b(cf[3]) << 16);
            uint2 pk; pk.x = p0; pk.y = p1;
            *(uint2*)&sPB[i * PB_PLANE + (bt * 16 + r16) * PB_ROW + jj * 4] = pk;
        }
        __syncthreads();

        {
            const bf16x8 z = (bf16x8){0,0,0,0,0,0,0,0};
            const bool lo = (kg < 2);
            bf16x8 a2[4], bb[4];
            #pragma unroll
            for (int mt = 0; mt < 4; ++mt)
                a2[mt] = lo ? *(const bf16x8*)&sPB[w * PB_PLANE + (mt * 16 + r16) * PB_ROW + kg * 8] : z;
            #pragma unroll
            for (int nt = 0; nt < 4; ++nt)
                bb[nt] = lo ? *(const bf16x8*)&sW2[c & 1][w * W2_PLANE + (nt * 16 + r16) * W2_ROW + kg * 8] : z;
            #pragma unroll
            for (int mt = 0; mt < 4; ++mt)
                #pragma unroll
                for (int nt = 0; nt < 4; ++nt)
                    acc[mt][nt] = __builtin_amdgcn_mfma_f32_16x16x32_bf16(
                        a2[mt], bb[nt], acc[mt][nt], 0, 0, 0);
        }

        if (c + 1 < CHUNKS) stage(c + 1, (c + 1) & 1);
        __syncthreads();
    }

    const int tabs = i0 + w;
    #pragma unroll
    for (int mt = 0; mt < 4; ++mt) {
        const int b = b0 + mt * 16 + kg * 4;
        #pragma unroll
        for (int nt = 0; nt < 4; ++nt) {
            const int e = nt * 16 + r16;
            #pragma unroll
            for (int r = 0; r < 4; ++r)
                unsafeAtomicAdd(&out[((size_t)(b + r) * T_ + tabs) * E_ + e],
                                acc[mt][nt][r]);
        }
    }
}

// ======================= host =======================

extern "C" void kernel_launch(void* const* d_in, const int* in_sizes, int n_in,
                              void* d_out, int out_size, void* d_ws, size_t ws_size,
                              hipStream_t stream) {
    const float* x  = (const float*)d_in[0];
    const float* W1 = (const float*)d_in[1];
    const float* b1 = (const float*)d_in[2];
    const float* W2 = (const float*)d_in[3];
    const float* b2 = (const float*)d_in[4];
    float* out = (float*)d_out;
    (void)in_sizes; (void)n_in; (void)out_size;

    const size_t xT_b   = 8388608ull;     // 256*256*64*2
    const size_t w2z_b  = 33554432ull;    // 256*64*1024*2
    const size_t H_full = 134217728ull;   // 256*32*256*32*2

    int NS = 0;
    if (d_ws) {
        const int cands[4] = {1, 2, 4, 8};
        for (int ci = 0; ci < 4; ++ci) {
            if (ws_size >= xT_b + w2z_b + H_full / cands[ci]) { NS = cands[ci]; break; }
        }
    }

    if (NS) {
        unsigned short* xT  = (unsigned short*)d_ws;
        unsigned short* W2Z = (unsigned short*)((char*)d_ws + xT_b);
        unsigned short* H   = (unsigned short*)((char*)d_ws + xT_b + w2z_b);

        hipLaunchKernelGGL(xcast_kernel, dim3(1024), dim3(256), 0, stream, x, xT);
        hipLaunchKernelGGL(w2z_kernel, dim3(2048), dim3(512), 0, stream, W2, W2Z);

        const int TS = 256 / NS;
        const int n_it = TS / 16;
        for (int s = 0; s < NS; ++s) {
            hipLaunchKernelGGL(phaseA2_kernel, dim3(32, n_it, 2), dim3(256), 0, stream,
                               xT, W1, b1, H, s * TS, n_it);
            hipLaunchKernelGGL(phaseB_kernel, dim3(TS * 2), dim3(512), 0, stream,
                               H, W2Z, b2, out, s * TS);
        }
    } else {
        const bool xbf = d_ws && ws_size >= xT_b;
        hipLaunchKernelGGL(init_out_kernel, dim3(4096), dim3(256), 0, stream, b2, out);
        if (xbf) {
            hipLaunchKernelGGL(xcast_kernel, dim3(1024), dim3(256), 0, stream,
                               x, (unsigned short*)d_ws);
            hipLaunchKernelGGL(fused_forest_kernel<true>, dim3(512), dim3(512), 0, stream,
                               (const void*)d_ws, W1, b1, W2, out);
        } else {
            hipLaunchKernelGGL(fused_forest_kernel<false>, dim3(512), dim3(512), 0, stream,
                               (const void*)x, W1, b1, W2, out);
        }
    }
}

// Round 8
// 112.100 us; speedup vs baseline: 1.5257x; 1.5257x over previous
//
#include <hip/hip_runtime.h>

// Problem: B=256, T=256 trees, E=64, H=4.
// out[b,t,e] = sum_{j!=t,h} relu(x[b,j,:]·W1[t,j,:,h] + b1[t,j,h]) * W2[t,pos(j)*4+h,e] + b2[t,e]
//
// R8: fix phaseA register SPILL (R7: xf needed 128 VGPR, got 84 -> scratch).
//   phaseA3 block = 4 j x 16 trees x 128 b -> xf = 64 VGPR, launch_bounds(256,4), no spill.
//   H layout [i][64 jq][256 b][16 k]: writes/reads are 4KB contiguous lane-contiguous spans.
//   W1 staged 64B/thread (full-line), sA double-buffered (latency hidden under compute).
// Fallback (small ws): R4 monolithic fused kernel.

namespace {

constexpr int T_ = 256;
constexpr int E_ = 64;
constexpr int K2_ = 1020;           // (T-1)*H

typedef float  f32x4  __attribute__((ext_vector_type(4)));
typedef short  bf16x8 __attribute__((ext_vector_type(8)));
typedef unsigned short u16x4 __attribute__((ext_vector_type(4)));

__device__ inline unsigned short f2b(float f) {
    union { float f; unsigned u; } v; v.f = f;
    unsigned r = v.u + 0x7fffu + ((v.u >> 16) & 1u);   // RNE bf16
    return (unsigned short)(r >> 16);
}

__device__ inline bf16x8 pack8(f32x4 a, f32x4 b) {
    bf16x8 r;
    r[0] = (short)f2b(a[0]); r[1] = (short)f2b(a[1]);
    r[2] = (short)f2b(a[2]); r[3] = (short)f2b(a[3]);
    r[4] = (short)f2b(b[0]); r[5] = (short)f2b(b[1]);
    r[6] = (short)f2b(b[2]); r[7] = (short)f2b(b[3]);
    return r;
}

// R4 fallback LDS geometry
constexpr int JC = 4;
constexpr int CHUNKS = 16;
constexpr int W1_ROW   = 72;
constexpr int W1_PLANE = 32 * W1_ROW + 8;
constexpr int PB_ROW   = 24;
constexpr int PB_PLANE = 64 * PB_ROW + 8;
constexpr int W2_ROW   = 16;
constexpr int W2_PLANE = 64 * W2_ROW + 8;

// phaseA3 LDS geometry
constexpr int SH_PLANE = 128 * 18 + 2;   // u16; plane shift = 577 words = 1 bank

} // namespace

// ======================= shared helpers =======================

// x[b][j][e] f32 -> xT[j][b][e] bf16
__global__ __launch_bounds__(256) void xcast_kernel(
    const float* __restrict__ x, unsigned short* __restrict__ xT)
{
    const int g     = blockIdx.x * 256 + threadIdx.x;   // 262,144
    const int part  = g & 3;                            // 16 e's each
    const int rowid = g >> 2;                           // = b*256 + j
    const int b = rowid >> 8, j = rowid & 255;
    const float* src = x + (size_t)rowid * E_ + part * 16;
    f32x4 v0 = *(const f32x4*)(src);
    f32x4 v1 = *(const f32x4*)(src + 4);
    f32x4 v2 = *(const f32x4*)(src + 8);
    f32x4 v3 = *(const f32x4*)(src + 12);
    unsigned short* dst = xT + ((size_t)j * 256 + b) * E_ + part * 16;
    *(bf16x8*)(dst)     = pack8(v0, v1);
    *(bf16x8*)(dst + 8) = pack8(v2, v3);
}

// out[b,t,e] = b2[t,e] (fallback path only)
__global__ __launch_bounds__(256) void init_out_kernel(
    const float* __restrict__ b2, float* __restrict__ out)
{
    const int idx = blockIdx.x * 256 + threadIdx.x;
    ((f32x4*)out)[idx] = ((const f32x4*)b2)[idx & 4095];
}

// ======================= two-phase path =======================

// W2[t][k][e] f32 -> W2Z[t][e][kz] bf16, kz = 4j+h, value = (j==t)?0:W2[t][pos(j)*4+h][e].
__global__ __launch_bounds__(512, 2) void w2z_kernel(
    const float* __restrict__ W2, unsigned short* __restrict__ W2Z)
{
    __shared__ __align__(16) unsigned short sT[64][136];
    const int bid = blockIdx.x;
    const int t = bid >> 3, kb = bid & 7;               // 8 k-blocks of 128
    const int tid = threadIdx.x;
    {
        const int kl = tid >> 2;            // 0..127 (block-local dst k)
        const int e0 = (tid & 3) << 4;      // 0,16,32,48
        const int k  = kb * 128 + kl;       // dst kz, 0..1023
        const int j  = k >> 2, h = k & 3;
        f32x4 v0 = {0,0,0,0}, v1 = {0,0,0,0}, v2 = {0,0,0,0}, v3 = {0,0,0,0};
        if (j != t) {
            const int ksrc = ((j < t) ? j : j - 1) * 4 + h;   // 0..1019
            const float* src = W2 + ((size_t)t * K2_ + ksrc) * E_ + e0;
            v0 = *(const f32x4*)(src);
            v1 = *(const f32x4*)(src + 4);
            v2 = *(const f32x4*)(src + 8);
            v3 = *(const f32x4*)(src + 12);
        }
        #pragma unroll
        for (int m = 0; m < 4; ++m) {
            sT[e0 + m     ][kl] = f2b(v0[m]);
            sT[e0 + 4 + m ][kl] = f2b(v1[m]);
            sT[e0 + 8 + m ][kl] = f2b(v2[m]);
            sT[e0 + 12 + m][kl] = f2b(v3[m]);
        }
    }
    __syncthreads();
    {
        const int e  = tid >> 3;            // 0..63
        const int ko = tid & 7;             // 16 k's each
        const unsigned short* srow = &sT[e][ko * 16];
        bf16x8 a = *(const bf16x8*)(srow);
        bf16x8 b = *(const bf16x8*)(srow + 8);
        unsigned short* dst = W2Z + ((size_t)t * 64 + e) * 1024 + kb * 128 + ko * 16;
        *(bf16x8*)(dst)     = a;
        *(bf16x8*)(dst + 8) = b;
    }
}

// Phase A v3: grid (64 jq-swz, n_it, 2 bh), 256 threads (4 waves).
// Block: 4 j x 16 trees x 128 b. xf = 64 VGPR (no spill). Per iq (4 trees):
// MFMA (m=(il,h), n=b) -> sH[il][b][16k] -> 4KB-contiguous flush to H[i][jq][b][16].
__global__ __launch_bounds__(256, 4) void phaseA3_kernel(
    const unsigned short* __restrict__ xT,  // [j][b][e]
    const float* __restrict__ W1,           // [256][256][64][4]
    const float* __restrict__ b1,           // [256][256][4]
    unsigned short* __restrict__ H,         // [TS][64 jq][256 b][16 k]
    int i_gbase)
{
    __shared__ __align__(16) unsigned short sA[2][4][16][72];   // [buf][j][m][e] 18432B
    __shared__ __align__(16) unsigned short sHf[4 * SH_PLANE];  // [il][b][18]    18448B

    // jq swizzle: XCD x (= linear id % 8) owns jq in [8x, 8x+8) -> xT slice L2-resident;
    // bh/it partners of a jq are co-XCD (W1 L2-shared across bh).
    const int bx = blockIdx.x;                   // 0..63
    const int jq = ((bx & 7) << 3) | (bx >> 3);
    const int it = blockIdx.y;
    const int bh = blockIdx.z;
    const int j0 = jq * 4;

    const int tid = threadIdx.x;
    const int w = tid >> 6, lane = tid & 63, r16 = lane & 15, kg = lane >> 4;
    const int bW = w * 32;                       // wave's local b-base (of 128)

    // ---- x fragments, register-resident (64 VGPR) ----
    bf16x8 xf[4][2][2];
    #pragma unroll
    for (int j = 0; j < 4; ++j)
        #pragma unroll
        for (int nt = 0; nt < 2; ++nt) {
            const unsigned short* xr =
                xT + ((size_t)(j0 + j) * 256 + bh * 128 + bW + nt * 16 + r16) * 64 + kg * 8;
            xf[j][nt][0] = *(const bf16x8*)(xr);
            xf[j][nt][1] = *(const bf16x8*)(xr + 32);
        }

    // W1 stage: thread (p = il*4+j, seg 0..15) reads 64B contiguous (full lines).
    auto stage = [&](int iq, int buf) {
        const int p = tid >> 4, seg = tid & 15;
        const int il = p >> 2, j = p & 3;
        const int ig = i_gbase + it * 16 + iq * 4 + il;
        const float* src = W1 + (((size_t)ig * 256 + (j0 + j)) << 8) + seg * 16;
        f32x4 v0 = *(const f32x4*)(src);
        f32x4 v1 = *(const f32x4*)(src + 4);
        f32x4 v2 = *(const f32x4*)(src + 8);
        f32x4 v3 = *(const f32x4*)(src + 12);   // v[s][q]: e = seg*4+s, h = q
        #pragma unroll
        for (int h = 0; h < 4; ++h) {
            u16x4 pk = (u16x4){f2b(v0[h]), f2b(v1[h]), f2b(v2[h]), f2b(v3[h])};
            *(u16x4*)&sA[buf][j][il * 4 + h][seg * 4] = pk;
        }
    };

    // Flush sH -> H: lane-contiguous, 4KB contiguous span per il.
    auto flushH = [&](int iq) {
        #pragma unroll
        for (int t4 = 0; t4 < 4; ++t4) {
            const int idx = t4 * 256 + tid;       // 0..1023 over (il, b, q)
            const int q   = idx & 1;
            const int b   = (idx >> 1) & 127;
            const int il  = idx >> 8;
            const unsigned short* srow = &sHf[il * SH_PLANE + b * 18 + q * 8];
            uint4 v;
            v.x = *(const unsigned*)(srow);
            v.y = *(const unsigned*)(srow + 2);
            v.z = *(const unsigned*)(srow + 4);
            v.w = *(const unsigned*)(srow + 6);
            const int i = it * 16 + iq * 4 + il;
            *(uint4*)(H + (((size_t)i * 64 + jq) * 256 + bh * 128 + b) * 16 + q * 8) = v;
        }
    };

    stage(0, 0);
    __syncthreads();

    for (int iq = 0; iq < 4; ++iq) {
        const int buf = iq & 1;
        if (iq + 1 < 4) stage(iq + 1, buf ^ 1);   // next W1 tile: latency hidden
        if (iq > 0) flushH(iq - 1);               // previous results out
        __syncthreads();

        // ---- compute: D[m=(il,h)][n=b]; lane: il=kg, h=reg, b=nt*16+r16 ----
        #pragma unroll
        for (int j = 0; j < 4; ++j) {
            const unsigned short* ar = &sA[buf][j][r16][0];
            bf16x8 a0 = *(const bf16x8*)(ar + kg * 8);
            bf16x8 a1 = *(const bf16x8*)(ar + 32 + kg * 8);
            const int ig = i_gbase + it * 16 + iq * 4 + kg;
            f32x4 bias = *(const f32x4*)(b1 + (((size_t)ig << 8) + (j0 + j)) * 4);
            #pragma unroll
            for (int nt = 0; nt < 2; ++nt) {
                f32x4 acc = (f32x4){0.f, 0.f, 0.f, 0.f};
                acc = __builtin_amdgcn_mfma_f32_16x16x32_bf16(a0, xf[j][nt][0], acc, 0, 0, 0);
                acc = __builtin_amdgcn_mfma_f32_16x16x32_bf16(a1, xf[j][nt][1], acc, 0, 0, 0);
                float v0 = acc[0] + bias[0]; v0 = v0 > 0.f ? v0 : 0.f;
                float v1 = acc[1] + bias[1]; v1 = v1 > 0.f ? v1 : 0.f;
                float v2 = acc[2] + bias[2]; v2 = v2 > 0.f ? v2 : 0.f;
                float v3 = acc[3] + bias[3]; v3 = v3 > 0.f ? v3 : 0.f;
                unsigned short* dst =
                    &sHf[kg * SH_PLANE + (bW + nt * 16 + r16) * 18 + j * 4];
                *(unsigned*)(dst)     = (unsigned)f2b(v0) | ((unsigned)f2b(v1) << 16);
                *(unsigned*)(dst + 2) = (unsigned)f2b(v2) | ((unsigned)f2b(v3) << 16);
            }
        }
        __syncthreads();
    }
    flushH(3);
}

// Phase B: block = (tree, b-half). out[b][t][:] = sum_k H[t][b][k] W2Z[t][:][k] + b2.
// M=128, N=64, K=1024 (zero-padded) in 16 chunks of 64; persistent acc.
__global__ __launch_bounds__(512, 4) void phaseB_kernel(
    const unsigned short* __restrict__ H,    // [TS][64][256][16]
    const unsigned short* __restrict__ W2Z,  // [256][64][1024]
    const float* __restrict__ b2,            // [256][64]
    float* __restrict__ out,                 // [256][256][64]
    int i_base)
{
    __shared__ __align__(16) unsigned short sA[2][128][72];  // [b][kk] 36.9KB
    __shared__ __align__(16) unsigned short sB[2][64][72];   // [e][kk] 18.4KB

    const int bid = blockIdx.x;
    const int t_loc = bid >> 1;
    const int t  = i_base + t_loc;
    const int b0 = (bid & 1) << 7;
    const int tid = threadIdx.x;
    const int w = tid >> 6, lane = tid & 63, r16 = lane & 15, kg = lane >> 4;

    // chunk c covers kz [c*64,(c+1)*64) = jq's 4c..4c+3; all reads lane-contiguous.
    auto stageA = [&](int c, int pb) {
        #pragma unroll
        for (int half = 0; half < 2; ++half) {
            const int idx = half * 512 + tid;     // 0..1023 over (jql, b, q)
            const int q   = idx & 1;
            const int b   = (idx >> 1) & 127;
            const int jql = idx >> 8;             // 0..3
            const unsigned short* src =
                H + (((size_t)t_loc * 64 + c * 4 + jql) * 256 + b0 + b) * 16 + q * 8;
            bf16x8 v = *(const bf16x8*)src;
            *(bf16x8*)&sA[pb][b][jql * 16 + q * 8] = v;
        }
    };
    // contiguous copy: W2Z row [t][e][c*64 .. +64]
    auto stageB = [&](int c, int pb) {
        const int e = tid >> 3;       // 0..63
        const int q = tid & 7;        // 0..7
        bf16x8 v = *(const bf16x8*)(W2Z + ((size_t)t * 64 + e) * 1024 + c * 64 + q * 8);
        *(bf16x8*)&sB[pb][e][q * 8] = v;
    };

    stageA(0, 0); stageB(0, 0);
    __syncthreads();

    f32x4 acc[4];
    #pragma unroll
    for (int nt = 0; nt < 4; ++nt) acc[nt] = (f32x4){0.f, 0.f, 0.f, 0.f};

    for (int c = 0; c < 16; ++c) {
        const int pb = c & 1;
        if (c + 1 < 16) { stageA(c + 1, pb ^ 1); stageB(c + 1, pb ^ 1); }

        const unsigned short* ar = &sA[pb][w * 16 + r16][0];
        bf16x8 a0 = *(const bf16x8*)(ar + kg * 8);
        bf16x8 a1 = *(const bf16x8*)(ar + 32 + kg * 8);
        #pragma unroll
        for (int nt = 0; nt < 4; ++nt) {
            const unsigned short* br = &sB[pb][nt * 16 + r16][0];
            bf16x8 bb0 = *(const bf16x8*)(br + kg * 8);
            bf16x8 bb1 = *(const bf16x8*)(br + 32 + kg * 8);
            acc[nt] = __builtin_amdgcn_mfma_f32_16x16x32_bf16(a0, bb0, acc[nt], 0, 0, 0);
            acc[nt] = __builtin_amdgcn_mfma_f32_16x16x32_bf16(a1, bb1, acc[nt], 0, 0, 0);
        }
        __syncthreads();
    }

    #pragma unroll
    for (int nt = 0; nt < 4; ++nt) {
        const int e = nt * 16 + r16;
        const float bias = b2[(t << 6) + e];
        #pragma unroll
        for (int r = 0; r < 4; ++r) {
            const int b = b0 + w * 16 + kg * 4 + r;
            out[((size_t)b << 14) + (t << 6) + e] = acc[nt][r] + bias;
        }
    }
}

// ======================= fallback: R4 monolithic fused kernel =======================

template <bool XBF>
__global__ __launch_bounds__(512, 4) void fused_forest_kernel(
    const void*  __restrict__ xv,
    const float* __restrict__ W1,
    const float* __restrict__ b1,
    const float* __restrict__ W2,
    float* __restrict__ out)
{
    __shared__ __align__(16) unsigned short sW1[4 * W1_PLANE];
    __shared__ __align__(16) unsigned short sPB[8 * PB_PLANE];
    __shared__ __align__(16) unsigned short sW2[2][8 * W2_PLANE];
    __shared__ __align__(16) float sB1[4][32];

    const int bid = blockIdx.x;
    const int xcd = bid & 7;
    const int rr  = bid >> 3;
    const int tgl = rr >> 4;
    const int bg  = (rr >> 2) & 3;
    const int jg  = rr & 3;
    const int tg  = tgl * 8 + xcd;
    const int i0  = tg << 3;
    const int b0  = bg << 6;
    const int j0g = jg << 6;

    const int tid  = threadIdx.x;
    const int w    = tid >> 6;
    const int lane = tid & 63;
    const int r16  = lane & 15;
    const int kg   = lane >> 4;
    const int bt   = w & 3;
    const int mh   = w >> 2;

    f32x4 acc[4][4];
    #pragma unroll
    for (int mt = 0; mt < 4; ++mt)
        #pragma unroll
        for (int nt = 0; nt < 4; ++nt)
            acc[mt][nt] = (f32x4){0.f, 0.f, 0.f, 0.f};

    auto stage = [&](int c, int pb) {
        const int j0 = j0g + c * JC;
        if (tid < 128) {
            const int jj = tid >> 5, ih = tid & 31;
            sB1[jj][ih] = b1[((i0 + (ih >> 2)) * T_ + (j0 + jj)) * 4 + (ih & 3)];
        }
        {
            const float* src = W1 + (((size_t)(i0 + w) * T_ + (j0 + kg)) * E_) * 4 + r16 * 16;
            f32x4 v0 = *(const f32x4*)(src);
            f32x4 v1 = *(const f32x4*)(src + 4);
            f32x4 v2 = *(const f32x4*)(src + 8);
            f32x4 v3 = *(const f32x4*)(src + 12);
            #pragma unroll
            for (int h = 0; h < 4; ++h) {
                u16x4 pk = (u16x4){f2b(v0[h]), f2b(v1[h]), f2b(v2[h]), f2b(v3[h])};
                *(u16x4*)&sW1[kg * W1_PLANE + (w * 4 + h) * W1_ROW + r16 * 4] = pk;
            }
        }
        {
            const int kk   = lane >> 2;
            const int e0   = (lane & 3) * 16;
            const int tabs = i0 + w;
            const int j    = j0 + (kk >> 2);
            unsigned short* dst = &sW2[pb][w * W2_PLANE + kk];
            if (j == tabs) {
                #pragma unroll
                for (int q = 0; q < 16; ++q) dst[(e0 + q) * W2_ROW] = 0;
            } else {
                const int ksrc = ((j < tabs) ? j : j - 1) * 4 + (kk & 3);
                const float* src = W2 + ((size_t)tabs * K2_ + ksrc) * E_ + e0;
                f32x4 v0 = *(const f32x4*)(src);
                f32x4 v1 = *(const f32x4*)(src + 4);
                f32x4 v2 = *(const f32x4*)(src + 8);
                f32x4 v3 = *(const f32x4*)(src + 12);
                #pragma unroll
                for (int q = 0; q < 4; ++q) {
                    dst[(e0 + q)      * W2_ROW] = f2b(v0[q]);
                    dst[(e0 + 4 + q)  * W2_ROW] = f2b(v1[q]);
                    dst[(e0 + 8 + q)  * W2_ROW] = f2b(v2[q]);
                    dst[(e0 + 12 + q) * W2_ROW] = f2b(v3[q]);
                }
            }
        }
    };

    stage(0, 0);
    __syncthreads();

    const int brow = b0 + bt * 16 + r16;

    for (int c = 0; c < CHUNKS; ++c) {
        const int j0 = j0g + c * JC;
        #pragma unroll
        for (int jj = 0; jj < JC; ++jj) {
            bf16x8 xa, xc;
            if (XBF) {
                const unsigned short* xr =
                    (const unsigned short*)xv + ((size_t)(j0 + jj) * 256 + brow) * E_;
                xa = *(const bf16x8*)(xr + kg * 8);
                xc = *(const bf16x8*)(xr + 32 + kg * 8);
            } else {
                const float* xr = (const float*)xv + ((size_t)brow * T_ + (j0 + jj)) * E_ + kg * 8;
                xa = pack8(*(const f32x4*)xr, *(const f32x4*)(xr + 4));
                xc = pack8(*(const f32x4*)(xr + 32), *(const f32x4*)(xr + 36));
            }
            const unsigned short* wr = &sW1[jj * W1_PLANE + (mh * 16 + r16) * W1_ROW];
            bf16x8 wa = *(const bf16x8*)(wr + kg * 8);
            bf16x8 wc = *(const bf16x8*)(wr + 32 + kg * 8);
            f32x4 cf = (f32x4){0.f, 0.f, 0.f, 0.f};
            cf = __builtin_amdgcn_mfma_f32_16x16x32_bf16(wa, xa, cf, 0, 0, 0);
            cf = __builtin_amdgcn_mfma_f32_16x16x32_bf16(wc, xc, cf, 0, 0, 0);
            const int i = mh * 4 + kg;
            f32x4 bias = *(const f32x4*)&sB1[jj][i * 4];
            #pragma unroll
            for (int r = 0; r < 4; ++r) {
                float vv = cf[r] + bias[r];
                cf[r] = vv > 0.f ? vv : 0.f;
            }
            unsigned p0 = (unsigned)f2b(cf[0]) | ((unsigned)f2b(cf[1]) << 16);
            unsigned p1 = (unsigned)f2b(cf[2]) | ((unsigned)f2b(cf[3]) << 16);
            uint2 pk; pk.x = p0; pk.y = p1;
            *(uint2*)&sPB[i * PB_PLANE + (bt * 16 + r16) * PB_ROW + jj * 4] = pk;
        }
        __syncthreads();

        {
            const bf16x8 z = (bf16x8){0,0,0,0,0,0,0,0};
            const bool lo = (kg < 2);
            bf16x8 a2[4], bb[4];
            #pragma unroll
            for (int mt = 0; mt < 4; ++mt)
                a2[mt] = lo ? *(const bf16x8*)&sPB[w * PB_PLANE + (mt * 16 + r16) * PB_ROW + kg * 8] : z;
            #pragma unroll
            for (int nt = 0; nt < 4; ++nt)
                bb[nt] = lo ? *(const bf16x8*)&sW2[c & 1][w * W2_PLANE + (nt * 16 + r16) * W2_ROW + kg * 8] : z;
            #pragma unroll
            for (int mt = 0; mt < 4; ++mt)
                #pragma unroll
                for (int nt = 0; nt < 4; ++nt)
                    acc[mt][nt] = __builtin_amdgcn_mfma_f32_16x16x32_bf16(
                        a2[mt], bb[nt], acc[mt][nt], 0, 0, 0);
        }

        if (c + 1 < CHUNKS) stage(c + 1, (c + 1) & 1);
        __syncthreads();
    }

    const int tabs = i0 + w;
    #pragma unroll
    for (int mt = 0; mt < 4; ++mt) {
        const int b = b0 + mt * 16 + kg * 4;
        #pragma unroll
        for (int nt = 0; nt < 4; ++nt) {
            const int e = nt * 16 + r16;
            #pragma unroll
            for (int r = 0; r < 4; ++r)
                unsafeAtomicAdd(&out[((size_t)(b + r) * T_ + tabs) * E_ + e],
                                acc[mt][nt][r]);
        }
    }
}

// ======================= host =======================

extern "C" void kernel_launch(void* const* d_in, const int* in_sizes, int n_in,
                              void* d_out, int out_size, void* d_ws, size_t ws_size,
                              hipStream_t stream) {
    const float* x  = (const float*)d_in[0];
    const float* W1 = (const float*)d_in[1];
    const float* b1 = (const float*)d_in[2];
    const float* W2 = (const float*)d_in[3];
    const float* b2 = (const float*)d_in[4];
    float* out = (float*)d_out;
    (void)in_sizes; (void)n_in; (void)out_size;

    const size_t xT_b   = 8388608ull;     // 256*256*64*2
    const size_t w2z_b  = 33554432ull;    // 256*64*1024*2
    const size_t H_full = 134217728ull;   // 256*64*256*16*2

    int NS = 0;
    if (d_ws) {
        const int cands[4] = {1, 2, 4, 8};
        for (int ci = 0; ci < 4; ++ci) {
            if (ws_size >= xT_b + w2z_b + H_full / cands[ci]) { NS = cands[ci]; break; }
        }
    }

    if (NS) {
        unsigned short* xT  = (unsigned short*)d_ws;
        unsigned short* W2Z = (unsigned short*)((char*)d_ws + xT_b);
        unsigned short* H   = (unsigned short*)((char*)d_ws + xT_b + w2z_b);

        hipLaunchKernelGGL(xcast_kernel, dim3(1024), dim3(256), 0, stream, x, xT);
        hipLaunchKernelGGL(w2z_kernel, dim3(2048), dim3(512), 0, stream, W2, W2Z);

        const int TS = 256 / NS;
        const int n_it = TS / 16;
        for (int s = 0; s < NS; ++s) {
            hipLaunchKernelGGL(phaseA3_kernel, dim3(64, n_it, 2), dim3(256), 0, stream,
                               xT, W1, b1, H, s * TS);
            hipLaunchKernelGGL(phaseB_kernel, dim3(TS * 2), dim3(512), 0, stream,
                               H, W2Z, b2, out, s * TS);
        }
    } else {
        const bool xbf = d_ws && ws_size >= xT_b;
        hipLaunchKernelGGL(init_out_kernel, dim3(4096), dim3(256), 0, stream, b2, out);
        if (xbf) {
            hipLaunchKernelGGL(xcast_kernel, dim3(1024), dim3(256), 0, stream,
                               x, (unsigned short*)d_ws);
            hipLaunchKernelGGL(fused_forest_kernel<true>, dim3(512), dim3(512), 0, stream,
                               (const void*)d_ws, W1, b1, W2, out);
        } else {
            hipLaunchKernelGGL(fused_forest_kernel<false>, dim3(512), dim3(512), 0, stream,
                               (const void*)x, W1, b1, W2, out);
        }
    }
}